// Round 9
// baseline (509.526 us; speedup 1.0000x reference)
//
#include <hip/hip_runtime.h>
#include <hip/hip_bf16.h>

// Problem constants (match reference)
#define NPTS 200000
#define BB   4
#define C3D  64
#define C2D  128
#define HH   96
#define WW   312
#define MID  128
#define OUTC 128

// bf16 weight sub-offsets (ushort elements)
#define WB_W1   0
#define WB_W2   8192
#define WB_AW1  24576
#define WB_AW2  57344
#define WB_FW   57472
#define WB_TOTAL 90240                     // ushorts = 45120 floats

// Fixed-point scale for deterministic integer atomics
#define FXS 1048576.0f
#define FXI (1.0 / 1048576.0)

// ws layout (float offsets). All stats are u64 fixed-point (2 floats each).
#define WS_H0S    45120                    // 2048 u64 (128 ch x 16 slots)
#define WS_H0Q    49216                    // 2048 u64
#define WS_SUM64  53440                    // 128*16 u64 (BN2 sums)
#define WS_SSQ64  57536                    // 128*16 u64 (BN2 ssq)
#define WS_STATS_END 61632
#define WS_IMG    62144                    // bf16 image, 15,335,424 ushorts

typedef __attribute__((ext_vector_type(8))) short s16x8;
typedef __attribute__((ext_vector_type(4))) float f32x4;

__device__ __forceinline__ ushort f2bf(float f) {
    unsigned u = __float_as_uint(f);
    unsigned r = (u + 0x7FFFu + ((u >> 16) & 1u)) >> 16;   // RNE
    return (ushort)r;
}
__device__ __forceinline__ float bf2f(ushort u) {
    return __uint_as_float(((unsigned)u) << 16);
}
__device__ __forceinline__ void atomic_fx(unsigned long long* p, float v) {
    atomicAdd(p, (unsigned long long)(long long)llrintf(v * FXS));
}
__device__ __forceinline__ s16x8 pack_bf8(float4 a, float4 b) {
    s16x8 v;
    v[0] = (short)f2bf(a.x); v[1] = (short)f2bf(a.y);
    v[2] = (short)f2bf(a.z); v[3] = (short)f2bf(a.w);
    v[4] = (short)f2bf(b.x); v[5] = (short)f2bf(b.y);
    v[6] = (short)f2bf(b.z); v[7] = (short)f2bf(b.w);
    return v;
}

// ---------------------------------------------------------------------------
// K1 (round-9): merged pre-pass.
//  blocks [0, TRANS_BLOCKS): image transpose (B,C,H,W)->(B,H,W,C) bf16 +
//    weight f32->bf16 packing (flat side job, first 353 blocks).
//  blocks [TRANS_BLOCKS, +H0_BLOCKS): BN1 stats = per-channel sum/ssq of
//    h0 = X@w1^T via MFMA (round-8 proven). Reads w1 f32 DIRECTLY and packs
//    per-wave (identical RNE conversion -> bit-identical fragments) because
//    wb is being written by sibling blocks (no intra-kernel ordering).
//  The 625 h0 blocks overlap under the 15360 transpose blocks.
//  Stats regions are pre-zeroed by hipMemsetAsync (launch-ordered).
// ---------------------------------------------------------------------------
#define TRANS_BLOCKS (BB * HH * 10 * 4)    // 15360
#define H0_ROWS   320
#define H0_BLOCKS (NPTS / H0_ROWS)         // 625

__global__ __launch_bounds__(256, 3) void k_pre(
        const float* __restrict__ img, ushort* __restrict__ img_bf,
        const float* __restrict__ w1, const float* __restrict__ w2,
        const float* __restrict__ aw1, const float* __restrict__ aw2,
        const float* __restrict__ fw, ushort* __restrict__ wb,
        const float* __restrict__ x,
        unsigned long long* __restrict__ hs64,
        unsigned long long* __restrict__ hq64) {
    __shared__ float tile[32][33];
    __shared__ float red[4][256];

    if (blockIdx.x >= TRANS_BLOCKS) {
        // ---------------- h0-stats path ----------------
        int hbid = blockIdx.x - TRANS_BLOCKS;
        int t = threadIdx.x, lane = t & 63, wv = t >> 6;
        int l15 = lane & 15, lq = lane >> 4;

        // pre-pack this wave's w1 fragments from f32 (loop-invariant)
        s16x8 wfa[8], wfb[8];
        #pragma unroll
        for (int nt = 0; nt < 8; nt++) {
            const float* wr = w1 + (nt * 16 + l15) * 64;
            float4 a0 = *(const float4*)(wr + lq * 8);
            float4 a1 = *(const float4*)(wr + lq * 8 + 4);
            float4 b0 = *(const float4*)(wr + 32 + lq * 8);
            float4 b1 = *(const float4*)(wr + 32 + lq * 8 + 4);
            wfa[nt] = pack_bf8(a0, a1);
            wfb[nt] = pack_bf8(b0, b1);
        }
        float psum[8], pssq[8];
        #pragma unroll
        for (int nt = 0; nt < 8; nt++) { psum[nt] = 0.f; pssq[nt] = 0.f; }

        int r0 = hbid * H0_ROWS;
        #pragma unroll 1
        for (int ch = 0; ch < 5; ch++) {
            const float* xr = x + (long)(r0 + ch * 64 + wv * 16 + l15) * C3D;
            float4 xa0 = *(const float4*)(xr + lq * 8);
            float4 xa1 = *(const float4*)(xr + lq * 8 + 4);
            float4 xb0 = *(const float4*)(xr + 32 + lq * 8);
            float4 xb1 = *(const float4*)(xr + 32 + lq * 8 + 4);
            s16x8 af0 = pack_bf8(xa0, xa1);
            s16x8 af1 = pack_bf8(xb0, xb1);
            #pragma unroll
            for (int nt = 0; nt < 8; nt++) {
                f32x4 acc = {0.f, 0.f, 0.f, 0.f};
                acc = __builtin_amdgcn_mfma_f32_16x16x32_bf16(af0, wfa[nt], acc, 0, 0, 0);
                acc = __builtin_amdgcn_mfma_f32_16x16x32_bf16(af1, wfb[nt], acc, 0, 0, 0);
                psum[nt] += acc[0] + acc[1] + acc[2] + acc[3];
                pssq[nt] += acc[0]*acc[0] + acc[1]*acc[1] + acc[2]*acc[2] + acc[3]*acc[3];
            }
        }
        #pragma unroll
        for (int nt = 0; nt < 8; nt++) {
            psum[nt] += __shfl_xor(psum[nt], 16, 64);
            psum[nt] += __shfl_xor(psum[nt], 32, 64);
            pssq[nt] += __shfl_xor(pssq[nt], 16, 64);
            pssq[nt] += __shfl_xor(pssq[nt], 32, 64);
        }
        if (lane < 16) {
            #pragma unroll
            for (int nt = 0; nt < 8; nt++) {
                red[wv][nt * 16 + l15]       = psum[nt];
                red[wv][128 + nt * 16 + l15] = pssq[nt];
            }
        }
        __syncthreads();
        {
            float v = red[0][t] + red[1][t] + red[2][t] + red[3][t];  // fixed order
            int c = t & 127;
            int slot = hbid & 15;
            if (t < 128) atomic_fx(&hs64[c * 16 + slot], v);
            else         atomic_fx(&hq64[c * 16 + slot], v);
        }
        return;
    }

    // ---------------- transpose path ----------------
    int flat = blockIdx.x * 256 + threadIdx.x;
    if (flat < WB_TOTAL) {
        float v;
        if      (flat < WB_W2)  v = w1[flat - WB_W1];
        else if (flat < WB_AW1) v = w2[flat - WB_W2];
        else if (flat < WB_AW2) v = aw1[flat - WB_AW1];
        else if (flat < WB_FW)  v = aw2[flat - WB_AW2];
        else                    v = fw[flat - WB_FW];
        wb[flat] = f2bf(v);
    }

    int bid = blockIdx.x;
    int ct = bid & 3;  bid >>= 2;          // 4 channel tiles
    int wt = bid % 10; bid /= 10;          // 10 width tiles
    int h  = bid % HH;
    int b  = bid / HH;
    int tx = threadIdx.x & 31, ty = threadIdx.x >> 5;   // 32 x 8
    int w0 = wt * 32, c0 = ct * 32;

    #pragma unroll
    for (int i = 0; i < 4; i++) {
        int c = c0 + ty + 8 * i;
        int w = w0 + tx;
        float v = 0.f;
        if (w < WW) v = img[((b * C2D + c) * HH + h) * WW + w];
        tile[ty + 8 * i][tx] = v;
    }
    __syncthreads();
    #pragma unroll
    for (int i = 0; i < 4; i++) {
        int w = w0 + ty + 8 * i;
        int c = c0 + tx;
        if (w < WW) img_bf[((b * HH + h) * WW + w) * C2D + c] = f2bf(tile[tx][ty + 8 * i]);
    }
}

// ---------------------------------------------------------------------------
// K4: fused main kernel (round-6 structure, 154 us, byte-identical phases) +
// round-9 prologue: BN1 finalize computed per-block from hs64/hq64 in fixed
// slot order (bit-identical across blocks, deterministic) into LDS — folds
// the former k_fin1 launch away.
// ---------------------------------------------------------------------------
__global__ __launch_bounds__(256, 3) void k_main(
    const float* __restrict__ x, const int* __restrict__ coords,
    const ushort* __restrict__ img_bf, const float* __restrict__ P2,
    const ushort* __restrict__ wb,
    const unsigned long long* __restrict__ hs64,
    const unsigned long long* __restrict__ hq64,
    const float* __restrict__ g1, const float* __restrict__ be1,
    const float* __restrict__ b2, const float* __restrict__ ab1,
    const float* __restrict__ ab2, const float* __restrict__ fb,
    float* __restrict__ out,
    unsigned long long* __restrict__ sum64, unsigned long long* __restrict__ ssq64)
{
    __shared__ __align__(16) char smem[34816];
    ushort* combs  = (ushort*)smem;          // 64 x 264 bf16 (33792 B)
    float*  outs   = (float*)smem;           // 64 x 132 f32 (same footprint)
    float*  a_part = (float*)(smem + 33792); // 4 x 64 f32 (1024 B)
    __shared__ float s_bn1s[128], s_bn1sh[128];

    const ushort* w1b  = wb + WB_W1;
    const ushort* w2b  = wb + WB_W2;
    const ushort* aw1b = wb + WB_AW1;
    const ushort* aw2b = wb + WB_AW2;
    const ushort* fwb  = wb + WB_FW;

    int t = threadIdx.x;
    int n0 = blockIdx.x * 64;
    int lane = t & 63, wv = t >> 6;
    int l15 = lane & 15, lq = lane >> 4;
    int m0 = wv * 16;
    int cb = wv * 32;                        // N-split column base

    // ---- P0: BN1 finalize prologue (former k_fin1, per-block redundant) ----
    if (t < 128) {
        long long si = 0, qi = 0;
        #pragma unroll
        for (int i = 0; i < 16; i++) {
            si += (long long)hs64[t * 16 + i];
            qi += (long long)hq64[t * 16 + i];
        }
        float S = (float)((double)si * FXI);
        float Q = (float)((double)qi * FXI);
        const float invN = 1.f / (float)NPTS;
        float m = S * invN;
        float v = Q * invN - m * m;
        float sc = g1[t] * rsqrtf(v + 1e-5f);
        s_bn1s[t] = sc;
        s_bn1sh[t] = be1[t] - m * sc;        // b1 cancels out of BN1 algebra
    }

    // ---- P1a: projection, per-lane (row = m0 + (lane>>2), 4x redundant) ----
    int grow = m0 + (lane >> 2);
    int qc = lane & 3;
    int poff_[4]; float pwgt_[4];
    {
        int4 cd = *(const int4*)(coords + (long)(n0 + grow) * 4);
        int b = cd.x;
        float p0 = (float)cd.y * 0.05f;
        float p1 = (float)cd.z * 0.05f - 40.f;
        float p2 = (float)cd.w * 0.1f - 3.f;
        const float* P = P2 + b * 12;
        float cam0 = P[0] * p0 + P[1] * p1 + P[2]  * p2 + P[3];
        float cam1 = P[4] * p0 + P[5] * p1 + P[6]  * p2 + P[7];
        float cam2 = P[8] * p0 + P[9] * p1 + P[10] * p2 + P[11];
        float d = cam2 + 1e-8f;
        float px = cam0 / d, py = cam1 / d;
        float gx = fminf(fmaxf(px / (float)WW * 2.f - 1.f, -1.f), 1.f);
        float gy = fminf(fmaxf(py / (float)HH * 2.f - 1.f, -1.f), 1.f);
        float ix = ((gx + 1.f) * (float)WW - 1.f) * 0.5f;
        float iy = ((gy + 1.f) * (float)HH - 1.f) * 0.5f;
        float x0f = floorf(ix), y0f = floorf(iy);
        float wx = ix - x0f, wy = iy - y0f;
        int x0 = (int)x0f, y0 = (int)y0f;
        #pragma unroll
        for (int j = 0; j < 4; j++) {
            int xc = x0 + (j & 1), yc = y0 + (j >> 1);
            float wgt = ((j & 1) ? wx : 1.f - wx) * ((j >> 1) ? wy : 1.f - wy);
            bool valid = (xc >= 0) && (xc < WW) && (yc >= 0) && (yc < HH);
            int xcc = min(max(xc, 0), WW - 1), ycc = min(max(yc, 0), HH - 1);
            poff_[j] = ((b * HH + ycc) * WW + xcc) * C2D;
            pwgt_[j] = valid ? wgt : 0.f;
        }
    }

    // ---- P1b: bilinear gather, ONE 8-channel group at a time (8 accs) ----
    #pragma unroll
    for (int g = 0; g < 4; g++) {
        float a8[8];
        #pragma unroll
        for (int e = 0; e < 8; e++) a8[e] = 0.f;
        #pragma unroll
        for (int j = 0; j < 4; j++) {
            s16x8 v = *(const s16x8*)(img_bf + poff_[j] + qc * 32 + g * 8);
            float wgt = pwgt_[j];
            #pragma unroll
            for (int e = 0; e < 8; e++)
                a8[e] += wgt * bf2f((ushort)v[e]);
        }
        s16x8 o;
        #pragma unroll
        for (int e = 0; e < 8; e++) o[e] = (short)f2bf(a8[e]);
        *(s16x8*)(combs + grow * 264 + 128 + qc * 32 + g * 8) = o;
    }

    // ---- P1c: GEMM1 A-operand: load from global, pack to bf16 ----
    s16x8 af0, af1;
    {
        const float* xr = x + (long)(n0 + m0 + l15) * C3D;
        float4 xa0 = *(const float4*)(xr + lq * 8);
        float4 xa1 = *(const float4*)(xr + lq * 8 + 4);
        float4 xb0 = *(const float4*)(xr + 32 + lq * 8);
        float4 xb1 = *(const float4*)(xr + 32 + lq * 8 + 4);
        af0 = pack_bf8(xa0, xa1);
        af1 = pack_bf8(xb0, xb1);
    }
    __syncthreads();   // B0: s_bn1s/s_bn1sh ready (and gather writes ordered)

    // ---- P1d: GEMM1 (K=64, M-split) + BN1 + relu -> combs[:, 0:128) ----
    #pragma unroll
    for (int nt = 0; nt < 8; nt++) {
        f32x4 acc = {0.f, 0.f, 0.f, 0.f};
        s16x8 bf0 = *(const s16x8*)(w1b + (nt * 16 + l15) * 64 + lq * 8);
        s16x8 bf1 = *(const s16x8*)(w1b + (nt * 16 + l15) * 64 + 32 + lq * 8);
        acc = __builtin_amdgcn_mfma_f32_16x16x32_bf16(af0, bf0, acc, 0, 0, 0);
        acc = __builtin_amdgcn_mfma_f32_16x16x32_bf16(af1, bf1, acc, 0, 0, 0);
        int c = nt * 16 + l15;
        float sc = s_bn1s[c], shf = s_bn1sh[c];
        #pragma unroll
        for (int r = 0; r < 4; r++)
            combs[(m0 + lq * 4 + r) * 264 + c] = f2bf(fmaxf(acc[r] * sc + shf, 0.f));
    }
    __syncthreads();   // B1: h + ifeat complete for ALL rows

    // ---- P2: GEMM2 N-split (wave's 32 cols x all 64 rows), w2 slice 8 KB ----
    f32x4 vacc[4][2];
    #pragma unroll
    for (int nt2 = 0; nt2 < 2; nt2++) {
        int c = cb + nt2 * 16 + l15;
        s16x8 wf[4];
        #pragma unroll
        for (int s = 0; s < 4; s++)
            wf[s] = *(const s16x8*)(w2b + c * 128 + s * 32 + lq * 8);
        #pragma unroll
        for (int mt = 0; mt < 4; mt++) {
            s16x8 ah[4];
            #pragma unroll
            for (int s = 0; s < 4; s++)
                ah[s] = *(const s16x8*)(combs + (mt * 16 + l15) * 264 + s * 32 + lq * 8);
            f32x4 acc = {0.f, 0.f, 0.f, 0.f};
            #pragma unroll
            for (int s = 0; s < 4; s++)
                acc = __builtin_amdgcn_mfma_f32_16x16x32_bf16(ah[s], wf[s], acc, 0, 0, 0);
            vacc[mt][nt2] = acc;
        }
    }
    __syncthreads();   // B2: all h reads done -> vfeat may overwrite h

    #pragma unroll
    for (int nt2 = 0; nt2 < 2; nt2++) {
        int c = cb + nt2 * 16 + l15;
        float bb = b2[c];
        #pragma unroll
        for (int mt = 0; mt < 4; mt++)
            #pragma unroll
            for (int r = 0; r < 4; r++)
                combs[(mt * 16 + lq * 4 + r) * 264 + c] = f2bf(vacc[mt][nt2][r] + bb);
    }
    __syncthreads();   // B3: vfeat complete; combs = [vfeat | ifeat]

    // ---- P3: att1 N-split, aw1 slice hoisted (16 KB once per wave) ----
    float sp[4][4];
    #pragma unroll
    for (int mt = 0; mt < 4; mt++)
        #pragma unroll
        for (int r = 0; r < 4; r++) sp[mt][r] = 0.f;
    #pragma unroll
    for (int nt2 = 0; nt2 < 2; nt2++) {
        int c = cb + nt2 * 16 + l15;
        s16x8 wf[8];
        #pragma unroll
        for (int s = 0; s < 8; s++)
            wf[s] = *(const s16x8*)(aw1b + c * 256 + s * 32 + lq * 8);
        float bb = ab1[c];
        float w2c = bf2f(aw2b[c]);
        #pragma unroll
        for (int mt = 0; mt < 4; mt++) {
            s16x8 afm[8];
            #pragma unroll
            for (int s = 0; s < 8; s++)
                afm[s] = *(const s16x8*)(combs + (mt * 16 + l15) * 264 + s * 32 + lq * 8);
            f32x4 acc = {0.f, 0.f, 0.f, 0.f};
            #pragma unroll
            for (int s = 0; s < 8; s++)
                acc = __builtin_amdgcn_mfma_f32_16x16x32_bf16(afm[s], wf[s], acc, 0, 0, 0);
            #pragma unroll
            for (int r = 0; r < 4; r++)
                sp[mt][r] += fmaxf(acc[r] + bb, 0.f) * w2c;
        }
    }
    #pragma unroll
    for (int d = 1; d < 16; d <<= 1) {
        #pragma unroll
        for (int mt = 0; mt < 4; mt++)
            #pragma unroll
            for (int r = 0; r < 4; r++)
                sp[mt][r] += __shfl_xor(sp[mt][r], d, 64);
    }
    if (l15 == 0) {
        #pragma unroll
        for (int mt = 0; mt < 4; mt++) {
            f32x4 v = {sp[mt][0], sp[mt][1], sp[mt][2], sp[mt][3]};
            *(f32x4*)(a_part + wv * 64 + mt * 16 + lq * 4) = v;
        }
    }
    __syncthreads();   // B4: a_part complete AND all att combs reads done

    // ---- P4: gate combs in place (wave-private rows), a computed per-lane ----
    {
        int row = m0 + l15;                // wave wv gates its own 16 rows
        float s0 = ab2[0] + a_part[row] + a_part[64 + row] + a_part[128 + row]
                 + a_part[192 + row];
        float a = 1.f / (1.f + expf(-s0));
        #pragma unroll
        for (int j = 0; j < 8; j++) {
            int ch = lq * 8 + j;           // 32 chunks of 8 cols per row
            float f = (ch < 16) ? a : 1.f - a;
            ushort* p = combs + row * 264 + ch * 8;
            s16x8 v = *(s16x8*)p;
            s16x8 o;
            #pragma unroll
            for (int e = 0; e < 8; e++) o[e] = (short)f2bf(bf2f((ushort)v[e]) * f);
            *(s16x8*)p = o;
        }
    }
    __syncthreads();   // B5: gated combs complete

    // ---- P5: fusion N-split (K=256), fw slice hoisted, ONE acc set ----
    f32x4 facc[4][2];
    #pragma unroll
    for (int nt2 = 0; nt2 < 2; nt2++) {
        int c = cb + nt2 * 16 + l15;
        s16x8 wf[8];
        #pragma unroll
        for (int s = 0; s < 8; s++)
            wf[s] = *(const s16x8*)(fwb + c * 256 + s * 32 + lq * 8);
        #pragma unroll
        for (int mt = 0; mt < 4; mt++) {
            s16x8 afm[8];
            #pragma unroll
            for (int s = 0; s < 8; s++)
                afm[s] = *(const s16x8*)(combs + (mt * 16 + l15) * 264 + s * 32 + lq * 8);
            f32x4 acc = {0.f, 0.f, 0.f, 0.f};
            #pragma unroll
            for (int s = 0; s < 8; s++)
                acc = __builtin_amdgcn_mfma_f32_16x16x32_bf16(afm[s], wf[s], acc, 0, 0, 0);
            facc[mt][nt2] = acc;
        }
    }
    __syncthreads();   // B6: all fusion reads done -> outs may alias combs

    #pragma unroll
    for (int nt2 = 0; nt2 < 2; nt2++) {
        int c = cb + nt2 * 16 + l15;
        float bb = fb[c];
        #pragma unroll
        for (int mt = 0; mt < 4; mt++)
            #pragma unroll
            for (int r = 0; r < 4; r++)
                outs[(mt * 16 + lq * 4 + r) * 132 + c] = facc[mt][nt2][r] + bb;
    }
    __syncthreads();   // B7: outs complete

    // ---- P6: coalesced global store + BN2 stats (fixed-point u64) ----
    {
        float4* og = (float4*)(out + (long)n0 * OUTC);
        #pragma unroll
        for (int i = 0; i < 8; i++) {
            int f4 = t + 256 * i;              // 2048 float4 = 64 rows x 32
            int row = f4 >> 5, c4 = f4 & 31;
            float4 v = *(const float4*)(outs + row * 132 + c4 * 4);
            og[row * 32 + c4] = v;
        }
        int slot = blockIdx.x & 15;
        if (t < 128) {
            float S = 0.f;
            #pragma unroll 8
            for (int row = 0; row < 64; row++) S += outs[row * 132 + t];
            atomic_fx(&sum64[t * 16 + slot], S);
        } else {
            int c = t - 128;
            float Q = 0.f;
            #pragma unroll 8
            for (int row = 0; row < 64; row++) { float v = outs[row * 132 + c]; Q += v * v; }
            atomic_fx(&ssq64[c * 16 + slot], Q);
        }
    }
}

// ---------------------------------------------------------------------------
// K6: BN2 finalize (per-block from 16-slot u64 sums, fixed order) + relu.
// ---------------------------------------------------------------------------
__global__ __launch_bounds__(256) void k_bnf(float* __restrict__ out,
                                             const unsigned long long* __restrict__ sum64,
                                             const unsigned long long* __restrict__ ssq64,
                                             const float* __restrict__ g,
                                             const float* __restrict__ b) {
    __shared__ float s_s[128], s_sh[128];
    int t = threadIdx.x;
    if (t < 128) {
        long long si = 0, qi = 0;
        #pragma unroll
        for (int i = 0; i < 16; i++) {
            si += (long long)sum64[t * 16 + i];
            qi += (long long)ssq64[t * 16 + i];
        }
        float S = (float)((double)si * FXI);
        float Q = (float)((double)qi * FXI);
        const float invN = 1.f / (float)NPTS;
        float m = S * invN;
        float v = Q * invN - m * m;
        float sc = g[t] * rsqrtf(v + 1e-5f);
        s_s[t] = sc;
        s_sh[t] = b[t] - m * sc;
    }
    __syncthreads();

    long i = (long)blockIdx.x * 256 + t;   // over 6.4M float4
    float4* p = (float4*)out;
    float4 v = p[i];
    int c4 = (int)(i & 31);
    float4 sv  = *(const float4*)(s_s + c4 * 4);
    float4 shv = *(const float4*)(s_sh + c4 * 4);
    v.x = fmaxf(v.x * sv.x + shv.x, 0.f);
    v.y = fmaxf(v.y * sv.y + shv.y, 0.f);
    v.z = fmaxf(v.z * sv.z + shv.z, 0.f);
    v.w = fmaxf(v.w * sv.w + shv.w, 0.f);
    p[i] = v;
}

// ---------------------------------------------------------------------------
extern "C" void kernel_launch(void* const* d_in, const int* in_sizes, int n_in,
                              void* d_out, int out_size, void* d_ws, size_t ws_size,
                              hipStream_t stream) {
    const float* x      = (const float*)d_in[0];
    const int*   coords = (const int*)d_in[1];
    const float* img    = (const float*)d_in[2];
    const float* P2     = (const float*)d_in[3];
    const float* w1     = (const float*)d_in[4];
    const float* b1     = (const float*)d_in[5];
    const float* g1     = (const float*)d_in[6];
    const float* be1    = (const float*)d_in[7];
    const float* w2     = (const float*)d_in[8];
    const float* b2     = (const float*)d_in[9];
    const float* aw1    = (const float*)d_in[10];
    const float* ab1    = (const float*)d_in[11];
    const float* aw2    = (const float*)d_in[12];
    const float* ab2    = (const float*)d_in[13];
    const float* fw     = (const float*)d_in[14];
    const float* fb     = (const float*)d_in[15];
    const float* gf     = (const float*)d_in[16];
    const float* bef    = (const float*)d_in[17];
    float* out = (float*)d_out;
    (void)b1;   // cancels out of BN1 algebra (mean-shift only)

    float* wsf = (float*)d_ws;
    ushort* wb = (ushort*)wsf;                                   // 90240 ushorts
    unsigned long long* hs64  = (unsigned long long*)(wsf + WS_H0S);
    unsigned long long* hq64  = (unsigned long long*)(wsf + WS_H0Q);
    unsigned long long* sum64 = (unsigned long long*)(wsf + WS_SUM64);
    unsigned long long* ssq64 = (unsigned long long*)(wsf + WS_SSQ64);
    ushort* img_bf = (ushort*)(wsf + WS_IMG);                    // 15,335,424 ushorts

    // zero all stat accumulators (graph-capture-safe async memset; the
    // harness's own reset() uses hipMemsetAsync)
    hipMemsetAsync(wsf + WS_H0S, 0, (size_t)(WS_STATS_END - WS_H0S) * 4, stream);
    // K1: transpose+weights (15360 blocks) ∪ h0-stats GEMM (625 blocks)
    k_pre<<<TRANS_BLOCKS + H0_BLOCKS, 256, 0, stream>>>(img, img_bf,
                                                        w1, w2, aw1, aw2, fw, wb,
                                                        x, hs64, hq64);
    // K2: fused main (BN1-finalize prologue folded in), 3125 blocks
    k_main<<<NPTS / 64, 256, 0, stream>>>(x, coords, img_bf, P2, wb,
                                          hs64, hq64, g1, be1,
                                          b2, ab1, ab2, fb, out, sum64, ssq64);
    // K3: BN2 finalize (per-block, deterministic) + relu
    k_bnf<<<NPTS * OUTC / 4 / 256, 256, 0, stream>>>(out, sum64, ssq64, gf, bef);
}

// Round 10
// 456.528 us; speedup vs baseline: 1.1161x; 1.1161x over previous
//
#include <hip/hip_runtime.h>
#include <hip/hip_bf16.h>

// Problem constants (match reference)
#define NPTS 200000
#define BB   4
#define C3D  64
#define C2D  128
#define HH   96
#define WW   312
#define MID  128
#define OUTC 128

// bf16 weight sub-offsets (ushort elements)
#define WB_W1   0
#define WB_W2   8192
#define WB_AW1  24576
#define WB_AW2  57344
#define WB_FW   57472
#define WB_TOTAL 90240                     // ushorts = 45120 floats

// Fixed-point scale for deterministic integer atomics
#define FXS 1048576.0f
#define FXI (1.0 / 1048576.0)

// ws layout (float offsets). All stats are u64 fixed-point (2 floats each).
#define WS_H0S    45120                    // 2048 u64 (128 ch x 16 slots)
#define WS_H0Q    49216                    // 2048 u64
#define WS_SUM64  53440                    // 128*16 u64 (BN2 sums)
#define WS_SSQ64  57536                    // 128*16 u64 (BN2 ssq)
#define WS_TICK   61628                    // 1 u32 ticket counter (in zero range)
#define ZERO_N    16512                    // floats to zero: 45120..61632
#define WS_DERIV  61632                    // s1,sh1 : 256
#define WS_IMG    62144                    // bf16 image, 15,335,424 ushorts

typedef __attribute__((ext_vector_type(8))) short s16x8;
typedef __attribute__((ext_vector_type(4))) float f32x4;

__device__ __forceinline__ ushort f2bf(float f) {
    unsigned u = __float_as_uint(f);
    unsigned r = (u + 0x7FFFu + ((u >> 16) & 1u)) >> 16;   // RNE
    return (ushort)r;
}
__device__ __forceinline__ float bf2f(ushort u) {
    return __uint_as_float(((unsigned)u) << 16);
}
__device__ __forceinline__ void atomic_fx(unsigned long long* p, float v) {
    atomicAdd(p, (unsigned long long)(long long)llrintf(v * FXS));
}
__device__ __forceinline__ long long atomic_read64(unsigned long long* p) {
    return (long long)atomicAdd(p, 0ULL);   // device-scope atomic read
}
__device__ __forceinline__ s16x8 pack_bf8(float4 a, float4 b) {
    s16x8 v;
    v[0] = (short)f2bf(a.x); v[1] = (short)f2bf(a.y);
    v[2] = (short)f2bf(a.z); v[3] = (short)f2bf(a.w);
    v[4] = (short)f2bf(b.x); v[5] = (short)f2bf(b.y);
    v[6] = (short)f2bf(b.z); v[7] = (short)f2bf(b.w);
    return v;
}

// ---------------------------------------------------------------------------
// K1: transpose image (B,C,H,W) -> (B,H,W,C) bf16; zero stats region;
//     convert weights to bf16 (merged k_prepw). Round-8 proven form.
// ---------------------------------------------------------------------------
__global__ __launch_bounds__(256) void k_transpose(const float* __restrict__ img,
                                                   ushort* __restrict__ img_bf,
                                                   float* __restrict__ stats,
                                                   const float* __restrict__ w1,
                                                   const float* __restrict__ w2,
                                                   const float* __restrict__ aw1,
                                                   const float* __restrict__ aw2,
                                                   const float* __restrict__ fw,
                                                   ushort* __restrict__ wb) {
    __shared__ float tile[32][33];
    int flat = blockIdx.x * 256 + threadIdx.x;
    if (flat < ZERO_N) stats[flat] = 0.f;
    if (flat < WB_TOTAL) {
        float v;
        if      (flat < WB_W2)  v = w1[flat - WB_W1];
        else if (flat < WB_AW1) v = w2[flat - WB_W2];
        else if (flat < WB_AW2) v = aw1[flat - WB_AW1];
        else if (flat < WB_FW)  v = aw2[flat - WB_AW2];
        else                    v = fw[flat - WB_FW];
        wb[flat] = f2bf(v);
    }

    int bid = blockIdx.x;
    int ct = bid & 3;  bid >>= 2;          // 4 channel tiles
    int wt = bid % 10; bid /= 10;          // 10 width tiles
    int h  = bid % HH;
    int b  = bid / HH;
    int tx = threadIdx.x & 31, ty = threadIdx.x >> 5;   // 32 x 8
    int w0 = wt * 32, c0 = ct * 32;

    #pragma unroll
    for (int i = 0; i < 4; i++) {
        int c = c0 + ty + 8 * i;
        int w = w0 + tx;
        float v = 0.f;
        if (w < WW) v = img[((b * C2D + c) * HH + h) * WW + w];
        tile[ty + 8 * i][tx] = v;
    }
    __syncthreads();
    #pragma unroll
    for (int i = 0; i < 4; i++) {
        int w = w0 + ty + 8 * i;
        int c = c0 + tx;
        if (w < WW) img_bf[((b * HH + h) * WW + w) * C2D + c] = f2bf(tile[tx][ty + 8 * i]);
    }
}

// ---------------------------------------------------------------------------
// K2: BN1 stats as h0 row-stats via MFMA (round-8 proven), plus round-10:
// LAST-BLOCK-DONE finalize. Each block bumps a device-scope ticket after its
// slot atomics + threadfence; the last block (ticket==H0_BLOCKS-1) re-reads
// the slots with atomic reads (XCD-coherence-safe) in the SAME fixed order
// as the former k_fin1 and writes s1/sh1 — folds that launch away without
// touching k_main.
// ---------------------------------------------------------------------------
#define H0_ROWS   320
#define H0_BLOCKS (NPTS / H0_ROWS)         // 625

__global__ __launch_bounds__(256) void k_h0stats(
        const float* __restrict__ x, const ushort* __restrict__ wb,
        unsigned long long* __restrict__ hs64,
        unsigned long long* __restrict__ hq64,
        unsigned* __restrict__ tick,
        const float* __restrict__ g, const float* __restrict__ be,
        float* __restrict__ s, float* __restrict__ sh) {
    __shared__ float red[4][256];          // [wave][c + 128*stat]
    __shared__ bool last;
    const ushort* w1b = wb + WB_W1;
    int t = threadIdx.x, lane = t & 63, wv = t >> 6;
    int l15 = lane & 15, lq = lane >> 4;
    float psum[8], pssq[8];
    #pragma unroll
    for (int nt = 0; nt < 8; nt++) { psum[nt] = 0.f; pssq[nt] = 0.f; }

    int r0 = blockIdx.x * H0_ROWS;
    #pragma unroll 1
    for (int ch = 0; ch < 5; ch++) {
        const float* xr = x + (long)(r0 + ch * 64 + wv * 16 + l15) * C3D;
        float4 xa0 = *(const float4*)(xr + lq * 8);
        float4 xa1 = *(const float4*)(xr + lq * 8 + 4);
        float4 xb0 = *(const float4*)(xr + 32 + lq * 8);
        float4 xb1 = *(const float4*)(xr + 32 + lq * 8 + 4);
        s16x8 af0 = pack_bf8(xa0, xa1);
        s16x8 af1 = pack_bf8(xb0, xb1);
        #pragma unroll
        for (int nt = 0; nt < 8; nt++) {
            f32x4 acc = {0.f, 0.f, 0.f, 0.f};
            s16x8 bf0 = *(const s16x8*)(w1b + (nt * 16 + l15) * 64 + lq * 8);
            s16x8 bf1 = *(const s16x8*)(w1b + (nt * 16 + l15) * 64 + 32 + lq * 8);
            acc = __builtin_amdgcn_mfma_f32_16x16x32_bf16(af0, bf0, acc, 0, 0, 0);
            acc = __builtin_amdgcn_mfma_f32_16x16x32_bf16(af1, bf1, acc, 0, 0, 0);
            psum[nt] += acc[0] + acc[1] + acc[2] + acc[3];
            pssq[nt] += acc[0]*acc[0] + acc[1]*acc[1] + acc[2]*acc[2] + acc[3]*acc[3];
        }
    }
    // reduce over lq (lanes sharing l15): channel totals for the wave's rows
    #pragma unroll
    for (int nt = 0; nt < 8; nt++) {
        psum[nt] += __shfl_xor(psum[nt], 16, 64);
        psum[nt] += __shfl_xor(psum[nt], 32, 64);
        pssq[nt] += __shfl_xor(pssq[nt], 16, 64);
        pssq[nt] += __shfl_xor(pssq[nt], 32, 64);
    }
    if (lane < 16) {
        #pragma unroll
        for (int nt = 0; nt < 8; nt++) {
            red[wv][nt * 16 + l15]       = psum[nt];
            red[wv][128 + nt * 16 + l15] = pssq[nt];
        }
    }
    __syncthreads();
    {
        float v = red[0][t] + red[1][t] + red[2][t] + red[3][t];  // fixed order
        int c = t & 127;
        int slot = blockIdx.x & 15;
        if (t < 128) atomic_fx(&hs64[c * 16 + slot], v);
        else         atomic_fx(&hq64[c * 16 + slot], v);
    }
    // ---- last-block-done BN1 finalize (former k_fin1, bit-identical) ----
    __threadfence();                       // slot atomics globally visible
    if (t == 0) last = (atomicAdd(tick, 1u) == H0_BLOCKS - 1);
    __syncthreads();
    if (last && t < 128) {
        long long si = 0, qi = 0;
        #pragma unroll
        for (int i = 0; i < 16; i++) {
            si += atomic_read64(&hs64[t * 16 + i]);
            qi += atomic_read64(&hq64[t * 16 + i]);
        }
        float S = (float)((double)si * FXI);
        float Q = (float)((double)qi * FXI);
        const float invN = 1.f / (float)NPTS;
        float m = S * invN;
        float v = Q * invN - m * m;
        float sc = g[t] * rsqrtf(v + 1e-5f);
        s[t] = sc;
        sh[t] = be[t] - m * sc;
    }
}

// ---------------------------------------------------------------------------
// K4: fused main kernel — ROUND-8 PROVEN FORM, byte-identical (154 us).
// ---------------------------------------------------------------------------
__global__ __launch_bounds__(256, 3) void k_main(
    const float* __restrict__ x, const int* __restrict__ coords,
    const ushort* __restrict__ img_bf, const float* __restrict__ P2,
    const ushort* __restrict__ wb,
    const float* __restrict__ bn1s, const float* __restrict__ bn1sh,
    const float* __restrict__ b2, const float* __restrict__ ab1,
    const float* __restrict__ ab2, const float* __restrict__ fb,
    float* __restrict__ out,
    unsigned long long* __restrict__ sum64, unsigned long long* __restrict__ ssq64)
{
    __shared__ __align__(16) char smem[34816];
    ushort* combs  = (ushort*)smem;          // 64 x 264 bf16 (33792 B)
    float*  outs   = (float*)smem;           // 64 x 132 f32 (same footprint)
    float*  a_part = (float*)(smem + 33792); // 4 x 64 f32 (1024 B)

    const ushort* w1b  = wb + WB_W1;
    const ushort* w2b  = wb + WB_W2;
    const ushort* aw1b = wb + WB_AW1;
    const ushort* aw2b = wb + WB_AW2;
    const ushort* fwb  = wb + WB_FW;

    int t = threadIdx.x;
    int n0 = blockIdx.x * 64;
    int lane = t & 63, wv = t >> 6;
    int l15 = lane & 15, lq = lane >> 4;
    int m0 = wv * 16;
    int cb = wv * 32;                        // N-split column base

    // ---- P1a: projection, per-lane (row = m0 + (lane>>2), 4x redundant) ----
    int grow = m0 + (lane >> 2);
    int qc = lane & 3;
    int poff_[4]; float pwgt_[4];
    {
        int4 cd = *(const int4*)(coords + (long)(n0 + grow) * 4);
        int b = cd.x;
        float p0 = (float)cd.y * 0.05f;
        float p1 = (float)cd.z * 0.05f - 40.f;
        float p2 = (float)cd.w * 0.1f - 3.f;
        const float* P = P2 + b * 12;
        float cam0 = P[0] * p0 + P[1] * p1 + P[2]  * p2 + P[3];
        float cam1 = P[4] * p0 + P[5] * p1 + P[6]  * p2 + P[7];
        float cam2 = P[8] * p0 + P[9] * p1 + P[10] * p2 + P[11];
        float d = cam2 + 1e-8f;
        float px = cam0 / d, py = cam1 / d;
        float gx = fminf(fmaxf(px / (float)WW * 2.f - 1.f, -1.f), 1.f);
        float gy = fminf(fmaxf(py / (float)HH * 2.f - 1.f, -1.f), 1.f);
        float ix = ((gx + 1.f) * (float)WW - 1.f) * 0.5f;
        float iy = ((gy + 1.f) * (float)HH - 1.f) * 0.5f;
        float x0f = floorf(ix), y0f = floorf(iy);
        float wx = ix - x0f, wy = iy - y0f;
        int x0 = (int)x0f, y0 = (int)y0f;
        #pragma unroll
        for (int j = 0; j < 4; j++) {
            int xc = x0 + (j & 1), yc = y0 + (j >> 1);
            float wgt = ((j & 1) ? wx : 1.f - wx) * ((j >> 1) ? wy : 1.f - wy);
            bool valid = (xc >= 0) && (xc < WW) && (yc >= 0) && (yc < HH);
            int xcc = min(max(xc, 0), WW - 1), ycc = min(max(yc, 0), HH - 1);
            poff_[j] = ((b * HH + ycc) * WW + xcc) * C2D;
            pwgt_[j] = valid ? wgt : 0.f;
        }
    }

    // ---- P1b: bilinear gather, ONE 8-channel group at a time (8 accs) ----
    #pragma unroll
    for (int g = 0; g < 4; g++) {
        float a8[8];
        #pragma unroll
        for (int e = 0; e < 8; e++) a8[e] = 0.f;
        #pragma unroll
        for (int j = 0; j < 4; j++) {
            s16x8 v = *(const s16x8*)(img_bf + poff_[j] + qc * 32 + g * 8);
            float wgt = pwgt_[j];
            #pragma unroll
            for (int e = 0; e < 8; e++)
                a8[e] += wgt * bf2f((ushort)v[e]);
        }
        s16x8 o;
        #pragma unroll
        for (int e = 0; e < 8; e++) o[e] = (short)f2bf(a8[e]);
        *(s16x8*)(combs + grow * 264 + 128 + qc * 32 + g * 8) = o;
    }

    // ---- P1c: GEMM1 A-operand: load from global, pack to bf16 ----
    s16x8 af0, af1;
    {
        const float* xr = x + (long)(n0 + m0 + l15) * C3D;
        float4 xa0 = *(const float4*)(xr + lq * 8);
        float4 xa1 = *(const float4*)(xr + lq * 8 + 4);
        float4 xb0 = *(const float4*)(xr + 32 + lq * 8);
        float4 xb1 = *(const float4*)(xr + 32 + lq * 8 + 4);
        af0 = pack_bf8(xa0, xa1);
        af1 = pack_bf8(xb0, xb1);
    }

    // ---- P1d: GEMM1 (K=64, M-split) + BN1 + relu -> combs[:, 0:128) ----
    #pragma unroll
    for (int nt = 0; nt < 8; nt++) {
        f32x4 acc = {0.f, 0.f, 0.f, 0.f};
        s16x8 bf0 = *(const s16x8*)(w1b + (nt * 16 + l15) * 64 + lq * 8);
        s16x8 bf1 = *(const s16x8*)(w1b + (nt * 16 + l15) * 64 + 32 + lq * 8);
        acc = __builtin_amdgcn_mfma_f32_16x16x32_bf16(af0, bf0, acc, 0, 0, 0);
        acc = __builtin_amdgcn_mfma_f32_16x16x32_bf16(af1, bf1, acc, 0, 0, 0);
        int c = nt * 16 + l15;
        float sc = bn1s[c], shf = bn1sh[c];
        #pragma unroll
        for (int r = 0; r < 4; r++)
            combs[(m0 + lq * 4 + r) * 264 + c] = f2bf(fmaxf(acc[r] * sc + shf, 0.f));
    }
    __syncthreads();   // B1: h + ifeat complete for ALL rows

    // ---- P2: GEMM2 N-split (wave's 32 cols x all 64 rows), w2 slice 8 KB ----
    f32x4 vacc[4][2];
    #pragma unroll
    for (int nt2 = 0; nt2 < 2; nt2++) {
        int c = cb + nt2 * 16 + l15;
        s16x8 wf[4];
        #pragma unroll
        for (int s = 0; s < 4; s++)
            wf[s] = *(const s16x8*)(w2b + c * 128 + s * 32 + lq * 8);
        #pragma unroll
        for (int mt = 0; mt < 4; mt++) {
            s16x8 ah[4];
            #pragma unroll
            for (int s = 0; s < 4; s++)
                ah[s] = *(const s16x8*)(combs + (mt * 16 + l15) * 264 + s * 32 + lq * 8);
            f32x4 acc = {0.f, 0.f, 0.f, 0.f};
            #pragma unroll
            for (int s = 0; s < 4; s++)
                acc = __builtin_amdgcn_mfma_f32_16x16x32_bf16(ah[s], wf[s], acc, 0, 0, 0);
            vacc[mt][nt2] = acc;
        }
    }
    __syncthreads();   // B2: all h reads done -> vfeat may overwrite h

    #pragma unroll
    for (int nt2 = 0; nt2 < 2; nt2++) {
        int c = cb + nt2 * 16 + l15;
        float bb = b2[c];
        #pragma unroll
        for (int mt = 0; mt < 4; mt++)
            #pragma unroll
            for (int r = 0; r < 4; r++)
                combs[(mt * 16 + lq * 4 + r) * 264 + c] = f2bf(vacc[mt][nt2][r] + bb);
    }
    __syncthreads();   // B3: vfeat complete; combs = [vfeat | ifeat]

    // ---- P3: att1 N-split, aw1 slice hoisted (16 KB once per wave) ----
    float sp[4][4];
    #pragma unroll
    for (int mt = 0; mt < 4; mt++)
        #pragma unroll
        for (int r = 0; r < 4; r++) sp[mt][r] = 0.f;
    #pragma unroll
    for (int nt2 = 0; nt2 < 2; nt2++) {
        int c = cb + nt2 * 16 + l15;
        s16x8 wf[8];
        #pragma unroll
        for (int s = 0; s < 8; s++)
            wf[s] = *(const s16x8*)(aw1b + c * 256 + s * 32 + lq * 8);
        float bb = ab1[c];
        float w2c = bf2f(aw2b[c]);
        #pragma unroll
        for (int mt = 0; mt < 4; mt++) {
            s16x8 afm[8];
            #pragma unroll
            for (int s = 0; s < 8; s++)
                afm[s] = *(const s16x8*)(combs + (mt * 16 + l15) * 264 + s * 32 + lq * 8);
            f32x4 acc = {0.f, 0.f, 0.f, 0.f};
            #pragma unroll
            for (int s = 0; s < 8; s++)
                acc = __builtin_amdgcn_mfma_f32_16x16x32_bf16(afm[s], wf[s], acc, 0, 0, 0);
            #pragma unroll
            for (int r = 0; r < 4; r++)
                sp[mt][r] += fmaxf(acc[r] + bb, 0.f) * w2c;
        }
    }
    #pragma unroll
    for (int d = 1; d < 16; d <<= 1) {
        #pragma unroll
        for (int mt = 0; mt < 4; mt++)
            #pragma unroll
            for (int r = 0; r < 4; r++)
                sp[mt][r] += __shfl_xor(sp[mt][r], d, 64);
    }
    if (l15 == 0) {
        #pragma unroll
        for (int mt = 0; mt < 4; mt++) {
            f32x4 v = {sp[mt][0], sp[mt][1], sp[mt][2], sp[mt][3]};
            *(f32x4*)(a_part + wv * 64 + mt * 16 + lq * 4) = v;
        }
    }
    __syncthreads();   // B4: a_part complete AND all att combs reads done

    // ---- P4: gate combs in place (wave-private rows), a computed per-lane ----
    {
        int row = m0 + l15;                // wave wv gates its own 16 rows
        float s0 = ab2[0] + a_part[row] + a_part[64 + row] + a_part[128 + row]
                 + a_part[192 + row];
        float a = 1.f / (1.f + expf(-s0));
        #pragma unroll
        for (int j = 0; j < 8; j++) {
            int ch = lq * 8 + j;           // 32 chunks of 8 cols per row
            float f = (ch < 16) ? a : 1.f - a;
            ushort* p = combs + row * 264 + ch * 8;
            s16x8 v = *(s16x8*)p;
            s16x8 o;
            #pragma unroll
            for (int e = 0; e < 8; e++) o[e] = (short)f2bf(bf2f((ushort)v[e]) * f);
            *(s16x8*)p = o;
        }
    }
    __syncthreads();   // B5: gated combs complete

    // ---- P5: fusion N-split (K=256), fw slice hoisted, ONE acc set ----
    f32x4 facc[4][2];
    #pragma unroll
    for (int nt2 = 0; nt2 < 2; nt2++) {
        int c = cb + nt2 * 16 + l15;
        s16x8 wf[8];
        #pragma unroll
        for (int s = 0; s < 8; s++)
            wf[s] = *(const s16x8*)(fwb + c * 256 + s * 32 + lq * 8);
        #pragma unroll
        for (int mt = 0; mt < 4; mt++) {
            s16x8 afm[8];
            #pragma unroll
            for (int s = 0; s < 8; s++)
                afm[s] = *(const s16x8*)(combs + (mt * 16 + l15) * 264 + s * 32 + lq * 8);
            f32x4 acc = {0.f, 0.f, 0.f, 0.f};
            #pragma unroll
            for (int s = 0; s < 8; s++)
                acc = __builtin_amdgcn_mfma_f32_16x16x32_bf16(afm[s], wf[s], acc, 0, 0, 0);
            facc[mt][nt2] = acc;
        }
    }
    __syncthreads();   // B6: all fusion reads done -> outs may alias combs

    #pragma unroll
    for (int nt2 = 0; nt2 < 2; nt2++) {
        int c = cb + nt2 * 16 + l15;
        float bb = fb[c];
        #pragma unroll
        for (int mt = 0; mt < 4; mt++)
            #pragma unroll
            for (int r = 0; r < 4; r++)
                outs[(mt * 16 + lq * 4 + r) * 132 + c] = facc[mt][nt2][r] + bb;
    }
    __syncthreads();   // B7: outs complete

    // ---- P6: coalesced global store + BN2 stats (fixed-point u64) ----
    {
        float4* og = (float4*)(out + (long)n0 * OUTC);
        #pragma unroll
        for (int i = 0; i < 8; i++) {
            int f4 = t + 256 * i;              // 2048 float4 = 64 rows x 32
            int row = f4 >> 5, c4 = f4 & 31;
            float4 v = *(const float4*)(outs + row * 132 + c4 * 4);
            og[row * 32 + c4] = v;
        }
        int slot = blockIdx.x & 15;
        if (t < 128) {
            float S = 0.f;
            #pragma unroll 8
            for (int row = 0; row < 64; row++) S += outs[row * 132 + t];
            atomic_fx(&sum64[t * 16 + slot], S);
        } else {
            int c = t - 128;
            float Q = 0.f;
            #pragma unroll 8
            for (int row = 0; row < 64; row++) { float v = outs[row * 132 + c]; Q += v * v; }
            atomic_fx(&ssq64[c * 16 + slot], Q);
        }
    }
}

// ---------------------------------------------------------------------------
// K6: BN2 finalize + relu. Round-10: grid-stride at 2048 blocks — the
// 25600-block version redundantly read the 32 KB slot table per block
// (~840 MB of L2 reads chip-wide); now /12.5.
// ---------------------------------------------------------------------------
#define BNF_BLOCKS 2048
#define BNF_TOTAL  (NPTS * OUTC / 4)       // 6.4M float4

__global__ __launch_bounds__(256) void k_bnf(float* __restrict__ out,
                                             const unsigned long long* __restrict__ sum64,
                                             const unsigned long long* __restrict__ ssq64,
                                             const float* __restrict__ g,
                                             const float* __restrict__ b) {
    __shared__ float s_s[128], s_sh[128];
    int t = threadIdx.x;
    if (t < 128) {
        long long si = 0, qi = 0;
        #pragma unroll
        for (int i = 0; i < 16; i++) {
            si += (long long)sum64[t * 16 + i];
            qi += (long long)ssq64[t * 16 + i];
        }
        float S = (float)((double)si * FXI);
        float Q = (float)((double)qi * FXI);
        const float invN = 1.f / (float)NPTS;
        float m = S * invN;
        float v = Q * invN - m * m;
        float sc = g[t] * rsqrtf(v + 1e-5f);
        s_s[t] = sc;
        s_sh[t] = b[t] - m * sc;
    }
    __syncthreads();

    float4* p = (float4*)out;
    for (long i = (long)blockIdx.x * 256 + t; i < BNF_TOTAL;
         i += (long)BNF_BLOCKS * 256) {
        float4 v = p[i];
        int c4 = (int)(i & 31);
        float4 sv  = *(const float4*)(s_s + c4 * 4);
        float4 shv = *(const float4*)(s_sh + c4 * 4);
        v.x = fmaxf(v.x * sv.x + shv.x, 0.f);
        v.y = fmaxf(v.y * sv.y + shv.y, 0.f);
        v.z = fmaxf(v.z * sv.z + shv.z, 0.f);
        v.w = fmaxf(v.w * sv.w + shv.w, 0.f);
        p[i] = v;
    }
}

// ---------------------------------------------------------------------------
extern "C" void kernel_launch(void* const* d_in, const int* in_sizes, int n_in,
                              void* d_out, int out_size, void* d_ws, size_t ws_size,
                              hipStream_t stream) {
    const float* x      = (const float*)d_in[0];
    const int*   coords = (const int*)d_in[1];
    const float* img    = (const float*)d_in[2];
    const float* P2     = (const float*)d_in[3];
    const float* w1     = (const float*)d_in[4];
    const float* b1     = (const float*)d_in[5];
    const float* g1     = (const float*)d_in[6];
    const float* be1    = (const float*)d_in[7];
    const float* w2     = (const float*)d_in[8];
    const float* b2     = (const float*)d_in[9];
    const float* aw1    = (const float*)d_in[10];
    const float* ab1    = (const float*)d_in[11];
    const float* aw2    = (const float*)d_in[12];
    const float* ab2    = (const float*)d_in[13];
    const float* fw     = (const float*)d_in[14];
    const float* fb     = (const float*)d_in[15];
    const float* gf     = (const float*)d_in[16];
    const float* bef    = (const float*)d_in[17];
    float* out = (float*)d_out;
    (void)b1;   // cancels out of BN1 algebra (mean-shift only)

    float* wsf = (float*)d_ws;
    ushort* wb = (ushort*)wsf;                                   // 90240 ushorts
    unsigned long long* hs64  = (unsigned long long*)(wsf + WS_H0S);
    unsigned long long* hq64  = (unsigned long long*)(wsf + WS_H0Q);
    unsigned long long* sum64 = (unsigned long long*)(wsf + WS_SUM64);
    unsigned long long* ssq64 = (unsigned long long*)(wsf + WS_SSQ64);
    unsigned* tick = (unsigned*)(wsf + WS_TICK);
    float* zero_base = wsf + WS_H0S;
    float* s1  = wsf + WS_DERIV;
    float* sh1 = s1 + 128;
    ushort* img_bf = (ushort*)(wsf + WS_IMG);                    // 15,335,424 ushorts

    // K1: transpose image (bf16) + zero stats/ticket + bf16 weights
    k_transpose<<<BB * HH * 10 * 4, 256, 0, stream>>>(img, img_bf, zero_base,
                                                      w1, w2, aw1, aw2, fw, wb);
    // K2: BN1 stats (h0 MFMA) + last-block-done finalize (folds k_fin1)
    k_h0stats<<<H0_BLOCKS, 256, 0, stream>>>(x, wb, hs64, hq64, tick,
                                             g1, be1, s1, sh1);
    // K3: fused main (MFMA), round-8 proven form, 3125 blocks
    k_main<<<NPTS / 64, 256, 0, stream>>>(x, coords, img_bf, P2, wb, s1, sh1,
                                          b2, ab1, ab2, fb, out, sum64, ssq64);
    // K4: BN2 finalize + relu, grid-stride 2048 blocks
    k_bnf<<<BNF_BLOCKS, 256, 0, stream>>>(out, sum64, ssq64, gf, bef);
}